// Round 7
// baseline (23152.606 us; speedup 1.0000x reference)
//
#include <hip/hip_runtime.h>
#include <math.h>

#define Bb 128
#define Nn 100
#define Ee 512
#define Hh 8
#define DHd 64
#define FFf 2048
#define Ll 6
#define STEPS 150

typedef _Float16 h8 __attribute__((ext_vector_type(8)));
typedef _Float16 h4 __attribute__((ext_vector_type(4)));
typedef float f4 __attribute__((ext_vector_type(4)));

// ---------------------------------------------------------------------------
// Split-f16 MFMA GEMM (encoder + prep).  C = A@B via Ah*Bh + Ah*Bl + Al*Bh.
// ---------------------------------------------------------------------------
template<bool RELU, bool BIAS, bool OUTF32, bool SPLITK>
__global__ __launch_bounds__(256) void mgemm_k(
    const _Float16* __restrict__ Ah, const _Float16* __restrict__ Al, int lda,
    const _Float16* __restrict__ Bh, const _Float16* __restrict__ Bl, int ldb,
    float* __restrict__ C, _Float16* __restrict__ Ch, _Float16* __restrict__ Cl,
    int ldc, const float* __restrict__ bias, int K, int kc, int Mtot)
{
  __shared__ _Float16 sm[4 * 5120];
  _Float16* sAh = sm;
  _Float16* sAl = sm + 5120;
  _Float16* sBh = sm + 10240;
  _Float16* sBl = sm + 15360;
  const int tid = threadIdx.x;
  const int m0 = blockIdx.y * 128, n0 = blockIdx.x * 128;
  const int k0 = SPLITK ? blockIdx.z * kc : 0;
  const int kEnd = SPLITK ? (k0 + kc) : K;
  const int lane = tid & 63, wave = tid >> 6;
  const int wm = wave >> 1, wn = wave & 1;
  const int m16 = lane & 15, kg = lane >> 4;
  f4 acc[4][4];
#pragma unroll
  for (int i = 0; i < 4; ++i)
#pragma unroll
    for (int j = 0; j < 4; ++j) acc[i][j] = (f4)0.f;

  for (int kt = k0; kt < kEnd; kt += 32) {
#pragma unroll
    for (int it = 0; it < 2; ++it) {
      int idx = tid + it * 256;
      int row = idx >> 2, g = idx & 3;
      int lo_ = row * 40 + g * 8;
      size_t ga = (size_t)(m0 + row) * lda + kt + g * 8;
      size_t gb = (size_t)(n0 + row) * ldb + kt + g * 8;
      *(h8*)(sAh + lo_) = *(const h8*)(Ah + ga);
      *(h8*)(sAl + lo_) = *(const h8*)(Al + ga);
      *(h8*)(sBh + lo_) = *(const h8*)(Bh + gb);
      *(h8*)(sBl + lo_) = *(const h8*)(Bl + gb);
    }
    __syncthreads();
    h8 a_h[4], a_l[4], b_h[4], b_l[4];
#pragma unroll
    for (int i = 0; i < 4; ++i) {
      int ro = (wm * 64 + i * 16 + m16) * 40 + kg * 8;
      int co = (wn * 64 + i * 16 + m16) * 40 + kg * 8;
      a_h[i] = *(const h8*)(sAh + ro);
      a_l[i] = *(const h8*)(sAl + ro);
      b_h[i] = *(const h8*)(sBh + co);
      b_l[i] = *(const h8*)(sBl + co);
    }
#pragma unroll
    for (int i = 0; i < 4; ++i)
#pragma unroll
      for (int j = 0; j < 4; ++j) {
        acc[i][j] = __builtin_amdgcn_mfma_f32_16x16x32_f16(a_h[i], b_h[j], acc[i][j], 0, 0, 0);
        acc[i][j] = __builtin_amdgcn_mfma_f32_16x16x32_f16(a_h[i], b_l[j], acc[i][j], 0, 0, 0);
        acc[i][j] = __builtin_amdgcn_mfma_f32_16x16x32_f16(a_l[i], b_h[j], acc[i][j], 0, 0, 0);
      }
    __syncthreads();
  }

  float* Cz = OUTF32 ? (C + (SPLITK ? (size_t)blockIdx.z * (size_t)Mtot * ldc : (size_t)0)) : C;
  int rb = m0 + wm * 64 + kg * 4;
  int cb = n0 + wn * 64 + m16;
#pragma unroll
  for (int j = 0; j < 4; ++j) {
    int col = cb + j * 16;
    float bv = BIAS ? bias[col] : 0.f;
#pragma unroll
    for (int i = 0; i < 4; ++i) {
#pragma unroll
      for (int r = 0; r < 4; ++r) {
        float v = acc[i][j][r] + bv;
        if (RELU) v = fmaxf(v, 0.f);
        int row = rb + i * 16 + r;
        if (OUTF32) {
          Cz[(size_t)row * ldc + col] = v;
        } else {
          _Float16 hh = (_Float16)v;
          Ch[(size_t)row * ldc + col] = hh;
          Cl[(size_t)row * ldc + col] = (_Float16)(v - (float)hh);
        }
      }
    }
  }
}

// ---------------------------------------------------------------------------
// Fused per-layer weight transpose+split: 6 weights in one launch.
// segs: 0..3 = 512x512 (256 blocks each), 4 = w1 512x2048 (1024), 5 = w2 2048x512 (1024)
// ---------------------------------------------------------------------------
struct W6 {
  const float* W[6];
  _Float16* Th[6];
  _Float16* Tl[6];
};

__global__ __launch_bounds__(256) void wconv6_k(W6 p)
{
  __shared__ float t[32][33];
  int id = blockIdx.x;
  int seg, l, bx, by, K, N;
  if (id < 1024)      { seg = id >> 8; l = id & 255; bx = l & 15; by = l >> 4; K = 512; N = 512; }
  else if (id < 2048) { seg = 4; l = id - 1024; bx = l & 63; by = l >> 6; K = 512; N = 2048; }
  else                { seg = 5; l = id - 2048; bx = l & 15; by = l >> 4; K = 2048; N = 512; }
  const float* W = p.W[seg];
  _Float16* Th = p.Th[seg];
  _Float16* Tl = p.Tl[seg];
  int n0 = bx * 32, k0 = by * 32;
  int tid = threadIdx.x;
  int r = tid >> 3, c4 = (tid & 7) * 4;
  float4 v = *(const float4*)(W + (size_t)(k0 + r) * N + n0 + c4);
  t[r][c4 + 0] = v.x; t[r][c4 + 1] = v.y; t[r][c4 + 2] = v.z; t[r][c4 + 3] = v.w;
  __syncthreads();
  h4 hi, lo;
#pragma unroll
  for (int i = 0; i < 4; ++i) {
    float x = t[c4 + i][r];
    _Float16 hh = (_Float16)x;
    hi[i] = hh;
    lo[i] = (_Float16)(x - (float)hh);
  }
  *(h4*)(Th + (size_t)(n0 + r) * K + k0 + c4) = hi;
  *(h4*)(Tl + (size_t)(n0 + r) * K + k0 + c4) = lo;
}

// single weight transpose+split (prep)
__global__ __launch_bounds__(256) void wconv_k(
    const float* __restrict__ W, int K, int N,
    _Float16* __restrict__ Th, _Float16* __restrict__ Tl)
{
  __shared__ float t[32][33];
  int n0 = blockIdx.x * 32, k0 = blockIdx.y * 32;
  int tid = threadIdx.x;
  int r = tid >> 3, c4 = (tid & 7) * 4;
  float4 v = *(const float4*)(W + (size_t)(k0 + r) * N + n0 + c4);
  t[r][c4 + 0] = v.x; t[r][c4 + 1] = v.y; t[r][c4 + 2] = v.z; t[r][c4 + 3] = v.w;
  __syncthreads();
  h4 hi, lo;
#pragma unroll
  for (int i = 0; i < 4; ++i) {
    float x = t[c4 + i][r];
    _Float16 hh = (_Float16)x;
    hi[i] = hh;
    lo[i] = (_Float16)(x - (float)hh);
  }
  *(h4*)(Th + (size_t)(n0 + r) * K + k0 + c4) = hi;
  *(h4*)(Tl + (size_t)(n0 + r) * K + k0 + c4) = lo;
}

// Permuted gates weight (proven r6): WgT row n' = j*16+q*4+r <- stacked col q*512+j*4+r
__global__ __launch_bounds__(256) void wconvg_k(
    const float* __restrict__ Wa, const float* __restrict__ Wb,
    _Float16* __restrict__ Th, _Float16* __restrict__ Tl)
{
  int np = blockIdx.x;
  int j = np >> 4, q = (np >> 2) & 3, r = np & 3;
  int n = q * 512 + j * 4 + r;
  int t = threadIdx.x;
#pragma unroll
  for (int kk = 0; kk < 4; ++kk) {
    int k = t + kk * 256;
    float x = (k < 512) ? Wa[(size_t)k * 2048 + n] : Wb[(size_t)(k - 512) * 2048 + n];
    _Float16 hh = (_Float16)x;
    Th[(size_t)np * 1024 + k] = hh;
    Tl[(size_t)np * 1024 + k] = (_Float16)(x - (float)hh);
  }
}

__global__ __launch_bounds__(256) void wsplit_k(
    const float* __restrict__ W, _Float16* __restrict__ Th, _Float16* __restrict__ Tl, int n)
{
  int i = blockIdx.x * 256 + threadIdx.x;
  if (i < n) {
    float x = W[i];
    _Float16 hh = (_Float16)x;
    Th[i] = hh;
    Tl[i] = (_Float16)(x - (float)hh);
  }
}

__global__ __launch_bounds__(256) void reduce4_k(
    const float* __restrict__ P, const float* __restrict__ bias, float* __restrict__ out)
{
  int idx = blockIdx.x * 256 + threadIdx.x;
  const size_t S = 3200ull * 512;
  float v = P[idx] + P[idx + S] + P[idx + 2 * S] + P[idx + 3 * S] + bias[idx & 511];
  out[idx] = v;
}

// ---------------------------------------------------------------------------
__global__ __launch_bounds__(256) void input_proj_k(
    const float* __restrict__ nf, const float* __restrict__ inw,
    const float* __restrict__ inb, const float* __restrict__ pe,
    float* __restrict__ x, _Float16* __restrict__ xh, _Float16* __restrict__ xl)
{
  int idx = blockIdx.x * 256 + threadIdx.x;
  int bn = idx >> 9, e = idx & 511;
  int n = bn - (bn / Nn) * Nn;
  const float* fr = nf + (size_t)bn * 8;
  float s = inb[e] + pe[(size_t)n * 512 + e];
#pragma unroll
  for (int i = 0; i < 8; ++i) s += fr[i] * inw[(size_t)i * 512 + e];
  x[idx] = s;
  _Float16 hh = (_Float16)s;
  xh[idx] = hh;
  xl[idx] = (_Float16)(s - (float)hh);
}

__global__ __launch_bounds__(256) void ln_k(
    const float* __restrict__ xin, const float* __restrict__ yin,
    const float* __restrict__ g, const float* __restrict__ bb,
    float* __restrict__ out, _Float16* __restrict__ oh, _Float16* __restrict__ ol)
{
  int row = blockIdx.x, t = threadIdx.x;
  __shared__ float red[256];
  size_t base = (size_t)row * 512;
  float v0 = xin[base + t] + yin[base + t];
  float v1 = xin[base + 256 + t] + yin[base + 256 + t];
  red[t] = v0 + v1;
  __syncthreads();
  for (int o = 128; o > 0; o >>= 1) { if (t < o) red[t] += red[t + o]; __syncthreads(); }
  float mu = red[0] * (1.f / 512.f);
  __syncthreads();
  float d0 = v0 - mu, d1 = v1 - mu;
  red[t] = d0 * d0 + d1 * d1;
  __syncthreads();
  for (int o = 128; o > 0; o >>= 1) { if (t < o) red[t] += red[t + o]; __syncthreads(); }
  float inv = 1.f / sqrtf(red[0] * (1.f / 512.f) + 1e-5f);
  float y0 = d0 * inv * g[t] + bb[t];
  float y1 = d1 * inv * g[t + 256] + bb[t + 256];
  out[base + t] = y0;
  out[base + 256 + t] = y1;
  _Float16 h0 = (_Float16)y0, h1 = (_Float16)y1;
  oh[base + t] = h0;           ol[base + t] = (_Float16)(y0 - (float)h0);
  oh[base + 256 + t] = h1;     ol[base + 256 + t] = (_Float16)(y1 - (float)h1);
}

// ---------------------------------------------------------------------------
__global__ __launch_bounds__(256) void enc_attn_k(
    const float* __restrict__ q, const float* __restrict__ k,
    const float* __restrict__ v, _Float16* __restrict__ oh, _Float16* __restrict__ ol)
{
  __shared__ __align__(16) float smem[14848];
  int bh = blockIdx.x; int b = bh >> 3, h = bh & 7;
  int t = threadIdx.x;
  float* qs = smem;
  float* kT = smem + 7616;
  float* p  = smem;
  const float* qg = q + ((size_t)b * Nn) * 512 + h * 64;
  const float* kg = k + ((size_t)b * Nn) * 512 + h * 64;
  const float* vg = v + ((size_t)b * Nn) * 512 + h * 64;
  for (int idx = t; idx < 6400; idx += 256) {
    int i = idx >> 6, d = idx & 63;
    qs[i * 68 + d]  = qg[(size_t)i * 512 + d];
    kT[d * 113 + i] = kg[(size_t)i * 512 + d];
  }
  __syncthreads();
  int ti = t >> 4, tj = t & 15;
  int i0 = ti * 7, j0 = tj * 7;
  float s[7][7];
#pragma unroll
  for (int r = 0; r < 7; ++r)
#pragma unroll
    for (int c = 0; c < 7; ++c) s[r][c] = 0.f;
  for (int kk = 0; kk < 64; ++kk) {
    float a[7], bb[7];
#pragma unroll
    for (int r = 0; r < 7; ++r) a[r] = qs[(i0 + r) * 68 + kk];
#pragma unroll
    for (int c = 0; c < 7; ++c) bb[c] = kT[kk * 113 + j0 + c];
#pragma unroll
    for (int r = 0; r < 7; ++r)
#pragma unroll
      for (int c = 0; c < 7; ++c) s[r][c] += a[r] * bb[c];
  }
  __syncthreads();
#pragma unroll
  for (int r = 0; r < 7; ++r)
#pragma unroll
    for (int c = 0; c < 7; ++c) {
      int i = i0 + r, j = j0 + c;
      if (i < Nn && j < Nn) p[i * 104 + j] = s[r][c] * 0.125f;
    }
  __syncthreads();
  int w = t >> 6, lane = t & 63;
  for (int i = w; i < Nn; i += 4) {
    float x0 = p[i * 104 + lane];
    float x1 = (lane < 36) ? p[i * 104 + 64 + lane] : -3.4e38f;
    float mx = fmaxf(x0, x1);
    for (int msk = 32; msk; msk >>= 1) mx = fmaxf(mx, __shfl_xor(mx, msk));
    float e0 = expf(x0 - mx);
    float e1 = (lane < 36) ? expf(x1 - mx) : 0.f;
    float ss = e0 + e1;
    for (int msk = 32; msk; msk >>= 1) ss += __shfl_xor(ss, msk);
    p[i * 104 + lane] = e0 / ss;
    if (lane < 36) p[i * 104 + 64 + lane] = e1 / ss;
  }
  __syncthreads();
  int d0 = tj * 4;
  float oa[7][4];
#pragma unroll
  for (int r = 0; r < 7; ++r)
#pragma unroll
    for (int c = 0; c < 4; ++c) oa[r][c] = 0.f;
  for (int j = 0; j < Nn; ++j) {
    float pr[7];
#pragma unroll
    for (int r = 0; r < 7; ++r) pr[r] = p[(i0 + r) * 104 + j];
    float4 vv = *(const float4*)(vg + (size_t)j * 512 + d0);
#pragma unroll
    for (int r = 0; r < 7; ++r) {
      oa[r][0] += pr[r] * vv.x; oa[r][1] += pr[r] * vv.y;
      oa[r][2] += pr[r] * vv.z; oa[r][3] += pr[r] * vv.w;
    }
  }
  size_t ob = ((size_t)b * Nn) * 512 + h * 64 + d0;
#pragma unroll
  for (int r = 0; r < 7; ++r)
    if (i0 + r < Nn) {
      h4 hv, lv;
#pragma unroll
      for (int c = 0; c < 4; ++c) {
        _Float16 hh = (_Float16)oa[r][c];
        hv[c] = hh;
        lv[c] = (_Float16)(oa[r][c] - (float)hh);
      }
      *(h4*)(oh + ob + (size_t)(i0 + r) * 512) = hv;
      *(h4*)(ol + ob + (size_t)(i0 + r) * 512) = lv;
    }
}

// sb2[m] = dpb . emb[m]
__global__ __launch_bounds__(256) void sb2_k(
    const float* __restrict__ emb, const float* __restrict__ dpb, float* __restrict__ sb2)
{
  int m = blockIdx.x * 4 + (threadIdx.x >> 6);
  int lane = threadIdx.x & 63;
  const float* er = emb + (size_t)m * 512;
  float s = 0.f;
  for (int e = lane; e < 512; e += 64) s += dpb[e] * er[e];
  for (int msk = 32; msk; msk >>= 1) s += __shfl_xor(s, msk);
  if (lane == 0) sb2[m] = s;
}

// decode init (proven r6)
__global__ __launch_bounds__(256) void init2_k(
    const float* __restrict__ emb, _Float16* __restrict__ ctxph, _Float16* __restrict__ ctxpl,
    float* __restrict__ ctxh, float* __restrict__ cbuf,
    int* visited, int* ucount, int* complete, int* allvis, int* first, int* prev,
    float* out)
{
  int b = blockIdx.x, t = threadIdx.x;
#pragma unroll
  for (int r = 0; r < 2; ++r) {
    int e = t + 256 * r;
    float s = 0.f;
    for (int i = 0; i < Nn; ++i) s += emb[((size_t)b * Nn + i) * 512 + e];
    s *= (1.f / 100.f);
    _Float16 hh = (_Float16)s;
    ctxph[b * 1024 + e] = hh;
    ctxpl[b * 1024 + e] = (_Float16)(s - (float)hh);
    ctxph[b * 1024 + 512 + e] = (_Float16)0.f;
    ctxpl[b * 1024 + 512 + e] = (_Float16)0.f;
    ctxh[(size_t)b * 1024 + 512 + e] = 0.f;
    cbuf[(size_t)b * 512 + e] = 0.f;
  }
  if (t < Nn) visited[b * Nn + t] = 0;
  if (t == 0) {
    ucount[b] = 0; complete[b] = 0; allvis[b] = 0; first[b] = 0; prev[b] = 0;
    out[150 * Bb + b] = 0.f;
  }
}

// ---------------------------------------------------------------------------
__device__ __forceinline__ float sigm(float x) { return 1.f / (1.f + expf(-x)); }

// P1 (verbatim r6): gates MFMA + fused LSTM + h2 planes + done partial.
__global__ __launch_bounds__(256) void ph1_k(
    const _Float16* __restrict__ ctxph, const _Float16* __restrict__ ctxpl,
    const _Float16* __restrict__ WgTh, const _Float16* __restrict__ WgTl,
    const float* __restrict__ bih, const float* __restrict__ bhh,
    float* __restrict__ cbuf, float* __restrict__ ctxh,
    _Float16* __restrict__ hph, _Float16* __restrict__ hpl,
    const float* __restrict__ done_w, float* __restrict__ ddp)
{
  __shared__ __align__(16) _Float16 sm[11520];
  __shared__ __align__(16) float gt[128 * 17];
  _Float16* sAh = sm;
  _Float16* sAl = sm + 5120;
  _Float16* sBh = sm + 10240;
  _Float16* sBl = sm + 10880;
  const int j = blockIdx.x, t = threadIdx.x;
  const int lane = t & 63, wave = t >> 6;
  const int m16 = lane & 15, kg = lane >> 4;
  f4 acc[2];
  acc[0] = (f4)0.f; acc[1] = (f4)0.f;

  for (int kt = 0; kt < 1024; kt += 32) {
#pragma unroll
    for (int it = 0; it < 2; ++it) {
      int idx = t + it * 256;
      int row = idx >> 2, g = idx & 3;
      int lo_ = row * 40 + g * 8;
      size_t ga = (size_t)row * 1024 + kt + g * 8;
      *(h8*)(sAh + lo_) = *(const h8*)(ctxph + ga);
      *(h8*)(sAl + lo_) = *(const h8*)(ctxpl + ga);
    }
    if (t < 64) {
      int row = t >> 2, g = t & 3;
      int lo_ = row * 40 + g * 8;
      size_t gb = (size_t)(j * 16 + row) * 1024 + kt + g * 8;
      *(h8*)(sBh + lo_) = *(const h8*)(WgTh + gb);
      *(h8*)(sBl + lo_) = *(const h8*)(WgTl + gb);
    }
    __syncthreads();
    h8 b_h = *(const h8*)(sBh + m16 * 40 + kg * 8);
    h8 b_l = *(const h8*)(sBl + m16 * 40 + kg * 8);
#pragma unroll
    for (int i = 0; i < 2; ++i) {
      int ro = ((wave * 2 + i) * 16 + m16) * 40 + kg * 8;
      h8 a_h = *(const h8*)(sAh + ro);
      h8 a_l = *(const h8*)(sAl + ro);
      acc[i] = __builtin_amdgcn_mfma_f32_16x16x32_f16(a_h, b_h, acc[i], 0, 0, 0);
      acc[i] = __builtin_amdgcn_mfma_f32_16x16x32_f16(a_h, b_l, acc[i], 0, 0, 0);
      acc[i] = __builtin_amdgcn_mfma_f32_16x16x32_f16(a_l, b_h, acc[i], 0, 0, 0);
    }
    __syncthreads();
  }
#pragma unroll
  for (int i = 0; i < 2; ++i) {
    int base = (wave * 2 + i) * 16 + kg * 4;
#pragma unroll
    for (int r = 0; r < 4; ++r)
      gt[(base + r) * 17 + m16] = acc[i][r];
  }
  __syncthreads();
  if (t < 128) {
    int b = t;
    float dsum = 0.f;
#pragma unroll
    for (int r = 0; r < 4; ++r) {
      int e = j * 4 + r;
      float ig = gt[b * 17 + 0 + r]  + bih[e]        + bhh[e];
      float fg = gt[b * 17 + 4 + r]  + bih[512 + e]  + bhh[512 + e];
      float gg = gt[b * 17 + 8 + r]  + bih[1024 + e] + bhh[1024 + e];
      float og = gt[b * 17 + 12 + r] + bih[1536 + e] + bhh[1536 + e];
      float cprev = cbuf[(size_t)b * 512 + e];
      float c2 = sigm(fg) * cprev + sigm(ig) * tanhf(gg);
      float h2 = sigm(og) * tanhf(c2);
      cbuf[(size_t)b * 512 + e] = c2;
      ctxh[(size_t)b * 1024 + 512 + e] = h2;
      _Float16 hh = (_Float16)h2;
      hph[b * 1024 + 512 + e] = hh;
      hpl[b * 1024 + 512 + e] = (_Float16)(h2 - (float)hh);
      dsum += h2 * done_w[e];
    }
    ddp[b * 128 + j] = dsum;
  }
}

// ---------------------------------------------------------------------------
// phB: per-b fused tail.  128 blocks x 512 threads, b = blockIdx.x.
// done-reduce + complete | q GEMV | attention | wo GEMV | LN | M2 scores | select.
// Reduction trees are 512-padded versions of r6's 256-trees (bit-identical sums).
// ---------------------------------------------------------------------------
__global__ __launch_bounds__(512) void phB_k(
    const float* __restrict__ ddp, const float* __restrict__ done_bp,
    const float* __restrict__ ctxh,
    const float* __restrict__ dwq, const float* __restrict__ dbq,
    const float* __restrict__ Kd, const float* __restrict__ Vd,
    const float* __restrict__ dwo, const float* __restrict__ dbo,
    const float* __restrict__ dlng, const float* __restrict__ dlnb,
    const float* __restrict__ M2, const float* __restrict__ sb2,
    const float* __restrict__ ew, const float* __restrict__ sbp,
    const float* __restrict__ rpp,
    const _Float16* __restrict__ embh, const _Float16* __restrict__ embl,
    int* visited, int* ucount, int* complete, int* allvis, int* first, int* prev,
    _Float16* __restrict__ ctxph, _Float16* __restrict__ ctxpl,
    float* __restrict__ out, int step)
{
  __shared__ float hs[512];
  __shared__ float qs[512];
  __shared__ float pb[8][104];
  __shared__ float os[512];
  __shared__ float av[512];
  __shared__ float red[512];
  __shared__ int  redi[512];
  __shared__ float sc[128];
  __shared__ int cflag;
  const int b = blockIdx.x, t = threadIdx.x;

  hs[t] = ctxh[(size_t)b * 1024 + 512 + t];
  // done-sum tree (bit-identical to r6's 128-partial tree)
  red[t] = (t < 128) ? ddp[b * 128 + t] : 0.f;
  __syncthreads();
  for (int o = 256; o > 0; o >>= 1) { if (t < o) red[t] += red[t + o]; __syncthreads(); }
  if (t == 0) {
    float z = red[0] + done_bp[0];
    int c = complete[b];
    if (!c && ucount[b] >= Nn && step >= Nn && z > 0.f) { c = 1; complete[b] = 1; }
    cflag = c;
  }
  __syncthreads();

  // q GEMV: qs[j] = dbq[j] + sum_k h[k] dwq[k][j]
  {
    float s = dbq[t];
    const float* wc = dwq + t;
#pragma unroll 4
    for (int k = 0; k < 512; ++k) s += hs[k] * wc[(size_t)k * 512];
    qs[t] = s;
  }
  __syncthreads();

  // attention: wave per head (h = t>>6), lane handles n=lane (+64)
  {
    int h = t >> 6, lanei = t & 63;
    const float* qh = qs + h * 64;
    float s1, s2 = -3.4e38f;
    {
      const float* kr = Kd + ((size_t)(b * Nn + lanei)) * 512 + h * 64;
      float s = 0.f;
#pragma unroll 4
      for (int d = 0; d < 64; ++d) s += qh[d] * kr[d];
      s1 = s * 0.125f;
    }
    int n2 = lanei + 64;
    if (n2 < Nn) {
      const float* kr = Kd + ((size_t)(b * Nn + n2)) * 512 + h * 64;
      float s = 0.f;
#pragma unroll 4
      for (int d = 0; d < 64; ++d) s += qh[d] * kr[d];
      s2 = s * 0.125f;
    }
    float mx = fmaxf(s1, s2);
    for (int m = 32; m; m >>= 1) mx = fmaxf(mx, __shfl_xor(mx, m));
    float e1 = expf(s1 - mx);
    float e2 = (n2 < Nn) ? expf(s2 - mx) : 0.f;
    float ss = e1 + e2;
    for (int m = 32; m; m >>= 1) ss += __shfl_xor(ss, m);
    pb[h][lanei] = e1 / ss;
    if (n2 < Nn) pb[h][n2] = e2 / ss;
    __syncthreads();
    float acc = 0.f;
    const float* vr = Vd + (size_t)(b * Nn) * 512 + h * 64 + lanei;
    for (int n = 0; n < Nn; ++n) acc += pb[h][n] * vr[(size_t)n * 512];
    os[h * 64 + lanei] = acc;
  }
  __syncthreads();

  // wo GEMV + LN (512-thread trees pair (t, t+256) = r6's v[0]+v[1])
  float v;
  {
    float s = dbo[t];
    const float* wc = dwo + t;
#pragma unroll 4
    for (int k = 0; k < 512; ++k) s += os[k] * wc[(size_t)k * 512];
    v = s;
  }
  red[t] = v; __syncthreads();
  for (int o = 256; o > 0; o >>= 1) { if (t < o) red[t] += red[t + o]; __syncthreads(); }
  float mu = red[0] * (1.f / 512.f);
  __syncthreads();
  float dv = v - mu;
  red[t] = dv * dv; __syncthreads();
  for (int o = 256; o > 0; o >>= 1) { if (t < o) red[t] += red[t + o]; __syncthreads(); }
  float inv = 1.f / sqrtf(red[0] * (1.f / 512.f) + 1e-5f);
  av[t] = dv * inv * dlng[t] + dlnb[t];
  __syncthreads();

  // scores via M2 (verbatim r6)
  if (t < Nn) {
    const float* m2r = M2 + ((size_t)(b * Nn + t)) * 512;
    float s = sb2[b * Nn + t];
    for (int jj = 0; jj < 512; ++jj) s += av[jj] * m2r[jj];
    int avz = allvis[b];
    if (!avz && visited[b * Nn + t]) s = rpp[0];
    if (avz) {
      int pvn = prev[b];
      float direct = ew[(size_t)b * 10000 + (size_t)pvn * 100];
      float via = ew[(size_t)b * 10000 + (size_t)pvn * 100 + t]
                + ew[(size_t)b * 10000 + (size_t)t * 100];
      if (via < direct) s += sbp[0] * (direct - via) / direct;
    }
    if (cflag) s = (t == first[b]) ? 100.f : -1e9f;
    sc[t] = s;
  }
  __syncthreads();

  // argmax + softmax (512-padded trees, same sums as r6)
  float vv = (t < Nn) ? sc[t] : -3.4e38f;
  int ii = (t < Nn) ? t : 0x7fffffff;
  red[t] = vv; redi[t] = ii;
  __syncthreads();
  for (int o = 256; o > 0; o >>= 1) {
    if (t < o) {
      float v2 = red[t + o]; int i2 = redi[t + o];
      if (v2 > red[t] || (v2 == red[t] && i2 < redi[t])) { red[t] = v2; redi[t] = i2; }
    }
    __syncthreads();
  }
  float m = red[0];
  int curr = redi[0];
  __syncthreads();
  float ex = (t < Nn) ? expf(sc[t] - m) : 0.f;
  red[t] = ex; __syncthreads();
  for (int o = 256; o > 0; o >>= 1) { if (t < o) red[t] += red[t + o]; __syncthreads(); }
  float Z = red[0];
  if (t == 0) {
    float pcur = expf(sc[curr] - m) / Z;
    out[step * Bb + b] = logf(pcur + 1e-10f);
    out[(151 + step) * Bb + b] = (float)curr;
    if (!cflag) {
      if (!visited[b * Nn + curr]) ucount[b] = ucount[b] + 1;
      visited[b * Nn + curr] = 1;
    }
    if (ucount[b] >= Nn) allvis[b] = 1;
    if (step == 0) first[b] = curr;
    prev[b] = curr;
  }
  size_t src = ((size_t)(b * Nn) + (size_t)curr) * 512;
  ctxph[b * 1024 + t] = embh[src + t];
  ctxpl[b * 1024 + t] = embl[src + t];
}

__global__ void final_k(const int* complete, const int* first, float* out)
{
  int b = threadIdx.x;
  out[(151 + 150) * Bb + b] = complete[b] ? 0.f : (float)first[b];
}

// ---------------------------------------------------------------------------
extern "C" void kernel_launch(void* const* d_in, const int* in_sizes, int n_in,
                              void* d_out, int out_size, void* d_ws, size_t ws_size,
                              hipStream_t stream)
{
  const float* nf      = (const float*)d_in[0];
  const float* ew      = (const float*)d_in[1];
  const float* pe      = (const float*)d_in[2];
  const float* in_w    = (const float*)d_in[3];
  const float* in_b    = (const float*)d_in[4];
  const float* enc_wq  = (const float*)d_in[5];
  const float* enc_wk  = (const float*)d_in[6];
  const float* enc_wv  = (const float*)d_in[7];
  const float* enc_wo  = (const float*)d_in[8];
  const float* enc_bq  = (const float*)d_in[9];
  const float* enc_bk  = (const float*)d_in[10];
  const float* enc_bv  = (const float*)d_in[11];
  const float* enc_bo  = (const float*)d_in[12];
  const float* enc_w1  = (const float*)d_in[13];
  const float* enc_b1  = (const float*)d_in[14];
  const float* enc_w2  = (const float*)d_in[15];
  const float* enc_b2  = (const float*)d_in[16];
  const float* ln1g    = (const float*)d_in[17];
  const float* ln1b    = (const float*)d_in[18];
  const float* ln2g    = (const float*)d_in[19];
  const float* ln2b    = (const float*)d_in[20];
  const float* wih     = (const float*)d_in[21];
  const float* whh     = (const float*)d_in[22];
  const float* bih     = (const float*)d_in[23];
  const float* bhh     = (const float*)d_in[24];
  const float* dwq     = (const float*)d_in[25];
  const float* dwk     = (const float*)d_in[26];
  const float* dwv     = (const float*)d_in[27];
  const float* dwo     = (const float*)d_in[28];
  const float* dpw     = (const float*)d_in[29];
  const float* dbq     = (const float*)d_in[30];
  const float* dbk     = (const float*)d_in[31];
  const float* dbv     = (const float*)d_in[32];
  const float* dbo     = (const float*)d_in[33];
  const float* dpb     = (const float*)d_in[34];
  const float* dlng    = (const float*)d_in[35];
  const float* dlnb    = (const float*)d_in[36];
  const float* sbp     = (const float*)d_in[37];
  const float* rpp     = (const float*)d_in[38];
  const float* done_w  = (const float*)d_in[39];
  const float* done_b  = (const float*)d_in[40];
  float* out = (float*)d_out;

  // ---- workspace carve (r6 layout) ----
  const size_t SZ = 12800ull * 512;
  float* ws = (float*)d_ws;
  float* x   = ws;
  float* xq  = x + SZ;                          // enc scratch -> M2
  float* xk  = xq + SZ;                         // enc k -> dec K
  float* xv  = xk + SZ;                         // enc v / ff2 partials -> dec V
  _Float16* xh = (_Float16*)(xv + SZ);          // node_emb planes
  _Float16* xl = xh + SZ;
  _Float16* oh = xl + SZ;                       // enc scratch planes
  _Float16* ol = oh + SZ;
  _Float16* wb = ol + SZ;                       // weight-plane region
  _Float16* wqh = wb;               _Float16* wql = wqh + 262144;
  _Float16* wkh = wql + 262144;     _Float16* wkl = wkh + 262144;
  _Float16* wvh = wkl + 262144;     _Float16* wvl = wvh + 262144;
  _Float16* woh_ = wvl + 262144;    _Float16* wol_ = woh_ + 262144;
  _Float16* w1h = wol_ + 262144;    _Float16* w1l = w1h + 1048576;
  _Float16* w2h = w1l + 1048576;    _Float16* w2l = w2h + 1048576;
  float* tail   = (float*)(w2l + 1048576);
  float* sb2    = tail;                         // 12800
  float* ddp    = sb2 + 12800;                  // 128*128
  float* obuf   = ddp + 16384;                  // (unused now)
  float* ctxh   = obuf + 65536;                 // 128*1024 (h half fp32)
  float* cbuf   = ctxh + 131072;                // 128*512
  _Float16* ctxph = (_Float16*)(cbuf + 65536);  // 128*1024 planes
  _Float16* ctxpl = ctxph + 131072;
  int* ivis     = (int*)(ctxpl + 131072);
  int* ucount   = ivis + 12800;
  int* complete = ucount + 128;
  int* allvis   = complete + 128;
  int* first    = allvis + 128;
  int* prev     = first + 128;
  float* M2 = xq;

  // ---- encoder (proven; wconv6 fusion is the only change) ----
  input_proj_k<<<25600, 256, 0, stream>>>(nf, in_w, in_b, pe, x, xh, xl);

  for (int l = 0; l < Ll; ++l) {
    const float* wq = enc_wq + (size_t)l * 262144;
    const float* wk = enc_wk + (size_t)l * 262144;
    const float* wv = enc_wv + (size_t)l * 262144;
    const float* wo = enc_wo + (size_t)l * 262144;
    const float* bq = enc_bq + (size_t)l * 512;
    const float* bk = enc_bk + (size_t)l * 512;
    const float* bv = enc_bv + (size_t)l * 512;
    const float* bo = enc_bo + (size_t)l * 512;
    const float* w1 = enc_w1 + (size_t)l * 1048576;
    const float* b1 = enc_b1 + (size_t)l * 2048;
    const float* w2 = enc_w2 + (size_t)l * 1048576;
    const float* b2 = enc_b2 + (size_t)l * 512;

    W6 wp;
    wp.W[0] = wq;  wp.Th[0] = wqh;  wp.Tl[0] = wql;
    wp.W[1] = wk;  wp.Th[1] = wkh;  wp.Tl[1] = wkl;
    wp.W[2] = wv;  wp.Th[2] = wvh;  wp.Tl[2] = wvl;
    wp.W[3] = wo;  wp.Th[3] = woh_; wp.Tl[3] = wol_;
    wp.W[4] = w1;  wp.Th[4] = w1h;  wp.Tl[4] = w1l;
    wp.W[5] = w2;  wp.Th[5] = w2h;  wp.Tl[5] = w2l;
    wconv6_k<<<3072, 256, 0, stream>>>(wp);

    mgemm_k<false, true, true, false><<<dim3(4, 100), 256, 0, stream>>>(
        xh, xl, 512, wqh, wql, 512, xq, nullptr, nullptr, 512, bq, 512, 0, 0);
    mgemm_k<false, true, true, false><<<dim3(4, 100), 256, 0, stream>>>(
        xh, xl, 512, wkh, wkl, 512, xk, nullptr, nullptr, 512, bk, 512, 0, 0);
    mgemm_k<false, true, true, false><<<dim3(4, 100), 256, 0, stream>>>(
        xh, xl, 512, wvh, wvl, 512, xv, nullptr, nullptr, 512, bv, 512, 0, 0);
    enc_attn_k<<<1024, 256, 0, stream>>>(xq, xk, xv, oh, ol);
    mgemm_k<false, true, true, false><<<dim3(4, 100), 256, 0, stream>>>(
        oh, ol, 512, woh_, wol_, 512, xq, nullptr, nullptr, 512, bo, 512, 0, 0);
    ln_k<<<12800, 256, 0, stream>>>(x, xq, ln1g + l * 512, ln1b + l * 512, x, xh, xl);
    for (int c = 0; c < 4; ++c) {
      mgemm_k<true, true, false, false><<<dim3(16, 25), 256, 0, stream>>>(
          xh + (size_t)c * 3200 * 512, xl + (size_t)c * 3200 * 512, 512,
          w1h, w1l, 512, nullptr, oh, ol, 2048, b1, 512, 0, 0);
      mgemm_k<false, false, true, true><<<dim3(4, 25, 4), 256, 0, stream>>>(
          oh, ol, 2048, w2h, w2l, 2048, xv, nullptr, nullptr, 512,
          nullptr, 2048, 512, 3200);
      reduce4_k<<<6400, 256, 0, stream>>>(xv, b2, xq + (size_t)c * 3200 * 512);
    }
    ln_k<<<12800, 256, 0, stream>>>(x, xq, ln2g + l * 512, ln2b + l * 512, x, xh, xl);
  }

  // ---- decode prep (proven r6) ----
  wconv_k<<<dim3(16, 16), 256, 0, stream>>>(dwk, 512, 512, wqh, wql);
  wconv_k<<<dim3(16, 16), 256, 0, stream>>>(dwv, 512, 512, wkh, wkl);
  mgemm_k<false, true, true, false><<<dim3(4, 100), 256, 0, stream>>>(
      xh, xl, 512, wqh, wql, 512, xk, nullptr, nullptr, 512, dbk, 512, 0, 0);
  mgemm_k<false, true, true, false><<<dim3(4, 100), 256, 0, stream>>>(
      xh, xl, 512, wkh, wkl, 512, xv, nullptr, nullptr, 512, dbv, 512, 0, 0);
  _Float16* WgTh = wb;
  _Float16* WgTl = WgTh + 2097152;
  _Float16* dpwNh = WgTl + 2097152;
  _Float16* dpwNl = dpwNh + 262144;
  wconvg_k<<<2048, 256, 0, stream>>>(wih, whh, WgTh, WgTl);
  wsplit_k<<<1024, 256, 0, stream>>>(dpw, dpwNh, dpwNl, 262144);
  mgemm_k<false, false, true, false><<<dim3(4, 100), 256, 0, stream>>>(
      xh, xl, 512, dpwNh, dpwNl, 512, M2, nullptr, nullptr, 512, nullptr, 512, 0, 0);
  sb2_k<<<3200, 256, 0, stream>>>(x, dpb, sb2);
  init2_k<<<128, 256, 0, stream>>>(x, ctxph, ctxpl, ctxh, cbuf, ivis, ucount,
                                   complete, allvis, first, prev, out);

  // ---- decode loop: 2 launches/step ----
  for (int step = 0; step < STEPS; ++step) {
    ph1_k<<<128, 256, 0, stream>>>(ctxph, ctxpl, WgTh, WgTl, bih, bhh,
                                   cbuf, ctxh, ctxph, ctxpl, done_w, ddp);
    phB_k<<<128, 512, 0, stream>>>(ddp, done_b, ctxh, dwq, dbq, xk, xv,
                                   dwo, dbo, dlng, dlnb, M2, sb2, ew, sbp, rpp,
                                   xh, xl, ivis, ucount, complete, allvis, first,
                                   prev, ctxph, ctxpl, out, step);
  }
  final_k<<<1, 128, 0, stream>>>(complete, first, out);
}